// Round 6
// baseline (179.507 us; speedup 1.0000x reference)
//
#include <hip/hip_runtime.h>
#include <cstdint>

#define NB1 8192
#define NB2 8192
#define DDIM 128
#define KROW 256           // stored row: [hi(128) | lo(128)] f16
#define NKITER 6           // virtual K = 384 in BK=64 steps

using half8   = __attribute__((ext_vector_type(8))) _Float16;
using half4   = __attribute__((ext_vector_type(4))) _Float16;
using float4v = __attribute__((ext_vector_type(4))) float;

typedef __attribute__((address_space(3))) void       lds_void;
typedef const __attribute__((address_space(1))) void glb_void;

__device__ inline unsigned long long packkey(float v, int j) {
  unsigned u = __float_as_uint(v);
  u = (u & 0x80000000u) ? ~u : (u | 0x80000000u);  // monotone float->uint
  return ((unsigned long long)u << 32) | (unsigned)j;
}

// virtual kt (BK=64 units) -> source 64-f16 unit within [hi(2u)|lo(2u)] row
// A: hi,lo,hi -> units 0,1,2,3,0,1 ; B: hi,hi,lo -> units 0,1,0,1,2,3
__device__ __forceinline__ int a_unit(int kt) { return (kt < 4) ? kt : kt - 4; }
__device__ __forceinline__ int b_unit(int kt) { return (kt < 2) ? kt : kt - 2; }

// ---------------------------------------------------------------------------
// Kernel 0: fp32 -> f16 hi/lo split + squared norms + init packed keys + cnt.
// ---------------------------------------------------------------------------
__global__ __launch_bounds__(256) void convert_kernel(
    const float* __restrict__ d1, const float* __restrict__ d2,
    _Float16* __restrict__ A2, _Float16* __restrict__ B2,
    float* __restrict__ asq, float* __restrict__ bsq,
    unsigned long long* __restrict__ packed, int* __restrict__ cnt) {
  int gid  = blockIdx.x * 256 + threadIdx.x;
  int wv   = gid >> 6;
  int lane = gid & 63;
  int rowc = 2 * wv + (lane >> 5);
  bool isA = rowc < NB1;
  const float* src = isA ? d1 : d2;
  int row = isA ? rowc : rowc - NB1;
  int k4  = (lane & 31) * 4;

  float4 v = *(const float4*)&src[row * DDIM + k4];
  _Float16 h0 = (_Float16)v.x, h1 = (_Float16)v.y;
  _Float16 h2 = (_Float16)v.z, h3 = (_Float16)v.w;
  half4 hh = {h0, h1, h2, h3};
  half4 ll = {(_Float16)(v.x - (float)h0), (_Float16)(v.y - (float)h1),
              (_Float16)(v.z - (float)h2), (_Float16)(v.w - (float)h3)};

  _Float16* dst = (isA ? A2 : B2) + (size_t)row * KROW;
  *(half4*)&dst[k4]       = hh;
  *(half4*)&dst[128 + k4] = ll;

  float s = v.x * v.x + v.y * v.y + v.z * v.z + v.w * v.w;
  #pragma unroll
  for (int off = 16; off > 0; off >>= 1) s += __shfl_xor(s, off, 64);
  if ((lane & 31) == 0) (isA ? asq : bsq)[row] = s;

  if (gid < NB1) packed[gid] = 0xFFFFFFFFFFFFFFFFull;  // +inf key
  if (gid < NB1 / 128) cnt[gid] = 0;                   // strip arrival counters
}

// ---------------------------------------------------------------------------
// Kernel 1: MFMA GEMM (virtual K=384 f16, fp32 acc) + fused argmin + output.
// 128x128 tile, BK=64 (6 barriers, 32 MFMA each), double-buffered 64 KB LDS.
// - Bank swizzle: chunk q (16B) of row r at slot (q + (r&7)) & 7 -> frag
//   b128 reads spread 16 lanes over 8 slots (2-way, free); staging stays
//   lane-linear (lane l -> row l>>3, slot l&7; fetches inverse-permuted
//   global chunk ((l&7)-(l>>3))&7).
// - Epilogue: register fold -> pad-17 LDS lex-min -> atomicMin(packed).
// - Last block per row-strip (threadfence + cnt atomicAdd) decodes packed
//   via no-op atomicMin reads and writes the final outputs (no out_kernel).
// ---------------------------------------------------------------------------
__global__ __launch_bounds__(256, 2) void mfma_match_kernel(
    const _Float16* __restrict__ A2, const _Float16* __restrict__ B2,
    const float* __restrict__ asq, const float* __restrict__ bsq,
    unsigned long long* __restrict__ packed, int* __restrict__ cnt,
    float* __restrict__ out) {
  __shared__ char smem_raw[65536];
  _Float16* Asb = (_Float16*)smem_raw;              // 2 buffers x 8192 f16
  _Float16* Bsb = (_Float16*)smem_raw + 16384;      // 2 buffers x 8192 f16
  unsigned long long* red = (unsigned long long*)smem_raw;  // [2][128][17] alias
  int* flagp = (int*)(smem_raw + 40960);

  const int t    = threadIdx.x;
  const int lane = t & 63;
  const int wid  = t >> 6;
  const int wm = wid >> 1, wn = wid & 1;
  const int lx = lane & 15, q = lane >> 4;

  // L2/XCD locality swizzle (dispatch round-robins id%8 across XCDs).
  const int id = blockIdx.x;
  const int xc = id & 7, kk = id >> 3;
  const int bx = ((kk >> 3) & 7) * 8 + xc;
  const int by = (kk & 7) + ((kk >> 6) & 7) * 8;
  const int row0 = bx * 128, col0 = by * 128;

  // Staging lane geometry (per 8-row instruction): row = l>>3, slot = l&7,
  // fetched global chunk = ((l&7) - (l>>3)) & 7.
  const int rowoff = lane >> 3;
  const int qch8   = ((((lane & 7) - (lane >> 3)) & 7)) * 8;

  float4v acc[4][4];
  #pragma unroll
  for (int r = 0; r < 4; ++r)
    #pragma unroll
    for (int c = 0; c < 4; ++c) acc[r][c] = (float4v){0.f, 0.f, 0.f, 0.f};

  float bq[4]; int jc[4];
  #pragma unroll
  for (int c = 0; c < 4; ++c) {
    jc[c] = col0 + wn * 64 + 16 * c + lx;
    bq[c] = bsq[jc[c]];
  }

  auto stage = [&](int kt, int buf) {
    const int au = a_unit(kt) * 64 + qch8;
    const int bu = b_unit(kt) * 64 + qch8;
    #pragma unroll
    for (int i = 0; i < 4; ++i) {
      int R = wid * 32 + i * 8;
      const _Float16* ga = A2 + (size_t)(row0 + R + rowoff) * KROW + au;
      __builtin_amdgcn_global_load_lds((glb_void*)ga,
          (lds_void*)(Asb + buf * 8192 + R * 64), 16, 0, 0);
      const _Float16* gb = B2 + (size_t)(col0 + R + rowoff) * KROW + bu;
      __builtin_amdgcn_global_load_lds((glb_void*)gb,
          (lds_void*)(Bsb + buf * 8192 + R * 64), 16, 0, 0);
    }
  };

  stage(0, 0);

  // Frag-read slots: logical chunk (4h+q) of row -> slot (4h+q+(lx&7)) & 7.
  const int s0 = ((q + (lx & 7)) & 7) * 8;       // h=0
  const int s1 = (((q + 4) + (lx & 7)) & 7) * 8; // h=1

  #pragma unroll
  for (int kt = 0; kt < NKITER; ++kt) {
    __syncthreads();  // stage(kt) drained (vmcnt0 before barrier); WAR safe
    if (kt < NKITER - 1) stage(kt + 1, (kt + 1) & 1);
    const _Float16* Ab = Asb + (kt & 1) * 8192;
    const _Float16* Bb = Bsb + (kt & 1) * 8192;
    half8 af[4][2], bf[4][2];
    #pragma unroll
    for (int r = 0; r < 4; ++r) {
      int rb = (wm * 64 + 16 * r + lx) * 64;
      af[r][0] = *(const half8*)&Ab[rb + s0];
      af[r][1] = *(const half8*)&Ab[rb + s1];
    }
    #pragma unroll
    for (int c = 0; c < 4; ++c) {
      int rb = (wn * 64 + 16 * c + lx) * 64;
      bf[c][0] = *(const half8*)&Bb[rb + s0];
      bf[c][1] = *(const half8*)&Bb[rb + s1];
    }
    #pragma unroll
    for (int r = 0; r < 4; ++r)
      #pragma unroll
      for (int c = 0; c < 4; ++c) {
        acc[r][c] = __builtin_amdgcn_mfma_f32_16x16x32_f16(
            af[r][0], bf[c][0], acc[r][c], 0, 0, 0);
        acc[r][c] = __builtin_amdgcn_mfma_f32_16x16x32_f16(
            af[r][1], bf[c][1], acc[r][c], 0, 0, 0);
      }
  }

  // ---- Epilogue. C/D layout: col = lane&15, row = q*4 + reg. ----
  __syncthreads();  // all frag reads done before aliasing staging LDS
  #pragma unroll
  for (int r = 0; r < 4; ++r) {
    #pragma unroll
    for (int reg = 0; reg < 4; ++reg) {
      float bv = 1e30f; int bj = 0;
      #pragma unroll
      for (int c = 0; c < 4; ++c) {  // jc ascending -> strict < keeps min j
        float val = fmaf(-2.f, acc[r][c][reg], bq[c]);
        if (val < bv) { bv = val; bj = jc[c]; }
      }
      int mrow = wm * 64 + 16 * r + 4 * q + reg;
      red[(wn * 128 + mrow) * 17 + lx] = packkey(bv, bj);
    }
  }
  __syncthreads();
  if (t < 128) {
    unsigned long long best = ~0ull;
    #pragma unroll
    for (int w = 0; w < 2; ++w)
      #pragma unroll
      for (int x = 0; x < 16; ++x) {
        unsigned long long k = red[(w * 128 + t) * 17 + x];
        if (k < best) best = k;
      }
    atomicMin(&packed[row0 + t], best);  // device-scope lex (val, idx) min
  }

  // ---- Last block of this row-strip decodes + writes outputs. ----
  __syncthreads();  // per-wave vmcnt(0) before barrier: atomics retired
  if (t == 0) {
    __threadfence();
    *flagp = (atomicAdd(&cnt[bx], 1) == NB2 / 128 - 1);
  }
  __syncthreads();
  if (*flagp && t < 128) {
    int r = row0 + t;
    unsigned long long best = atomicMin(&packed[r], ~0ull);  // coherent read
    unsigned u = (unsigned)(best >> 32);
    u = (u & 0x80000000u) ? (u & 0x7fffffffu) : ~u;  // invert monotone map
    float dist = sqrtf(fmaxf(asq[r] + __uint_as_float(u), 0.f));
    int j = (int)(unsigned)(best & 0xffffffffu);
    out[r] = dist;
    float2 mi = {(float)r, (float)j};
    *(float2*)&out[NB1 + 2 * r] = mi;
  }
}

extern "C" void kernel_launch(void* const* d_in, const int* in_sizes, int n_in,
                              void* d_out, int out_size, void* d_ws, size_t ws_size,
                              hipStream_t stream) {
  const float* d1 = (const float*)d_in[0];
  const float* d2 = (const float*)d_in[1];
  float* out = (float*)d_out;

  char* w = (char*)d_ws;
  float* asq = (float*)w;                                   // 32 KB
  float* bsq = (float*)(w + 32768);                         // 32 KB
  _Float16* A2 = (_Float16*)(w + 65536);                    // 4 MB
  _Float16* B2 = (_Float16*)(w + 65536 + 4194304);          // 4 MB
  unsigned long long* packed =
      (unsigned long long*)(w + 65536 + 2 * 4194304);       // 64 KB
  int* cnt = (int*)(w + 65536 + 2 * 4194304 + 65536);       // 256 B

  convert_kernel<<<(NB1 + NB2) / 8, 256, 0, stream>>>(
      d1, d2, A2, B2, asq, bsq, packed, cnt);

  mfma_match_kernel<<<(NB1 / 128) * (NB2 / 128), 256, 0, stream>>>(
      A2, B2, asq, bsq, packed, cnt, out);
}